// Round 1
// baseline (1037.475 us; speedup 1.0000x reference)
//
#include <hip/hip_runtime.h>
#include <stdint.h>

#define BB 8
#define NN 4096
#define HH 64
#define C2 128   // [x|h] concat width

typedef float f32x4 __attribute__((ext_vector_type(4)));
typedef __bf16 bf16x8 __attribute__((ext_vector_type(8)));
typedef unsigned int u32x4 __attribute__((ext_vector_type(4)));

__device__ __forceinline__ unsigned short f2bf(float x) {
  unsigned int u = __float_as_uint(x);
  u += 0x7FFFu + ((u >> 16) & 1u);   // RNE
  return (unsigned short)(u >> 16);
}
__device__ __forceinline__ unsigned int pack2(float a, float b) {
  return (unsigned int)f2bf(a) | ((unsigned int)f2bf(b) << 16);
}

// ---------------------------------------------------------------------------
// prepX: x,h [B][N][64] f32 -> XbfT [B][128][N] bf16 (row f: 0-63 = x, 64-127 = h)
// ---------------------------------------------------------------------------
__global__ __launch_bounds__(256) void k_prepX(const float* __restrict__ x,
                                               const float* __restrict__ h,
                                               unsigned short* __restrict__ XbfT) {
  __shared__ __align__(16) unsigned short lds[64 * 136];
  const int b = blockIdx.y;
  const int n0 = blockIdx.x * 64;
  const int t = threadIdx.x;
#pragma unroll
  for (int i = 0; i < 4; ++i) {
    int e = t + i * 256;           // 0..1023
    int n = e >> 4, f4 = e & 15;
    size_t src = (((size_t)b * NN + n0 + n) << 6) + f4 * 4;
    f32x4 vx = *(const f32x4*)(x + src);
    f32x4 vh = *(const f32x4*)(h + src);
    unsigned short* px = &lds[n * 136 + f4 * 4];
    px[0] = f2bf(vx.x); px[1] = f2bf(vx.y); px[2] = f2bf(vx.z); px[3] = f2bf(vx.w);
    unsigned short* ph = &lds[n * 136 + 64 + f4 * 4];
    ph[0] = f2bf(vh.x); ph[1] = f2bf(vh.y); ph[2] = f2bf(vh.z); ph[3] = f2bf(vh.w);
  }
  __syncthreads();
  const int f2 = t >> 1, half = t & 1;
  unsigned int w[16];
#pragma unroll
  for (int i = 0; i < 16; ++i) {
    int na = half * 32 + i * 2;
    w[i] = (unsigned int)lds[na * 136 + f2] | ((unsigned int)lds[(na + 1) * 136 + f2] << 16);
  }
  size_t off = ((size_t)b * C2 + f2) * NN + n0 + half * 32;
  u32x4* dst = (u32x4*)(XbfT + off);
  u32x4 v0 = {w[0], w[1], w[2], w[3]};   dst[0] = v0;
  u32x4 v1 = {w[4], w[5], w[6], w[7]};   dst[1] = v1;
  u32x4 v2 = {w[8], w[9], w[10], w[11]}; dst[2] = v2;
  u32x4 v3 = {w[12], w[13], w[14], w[15]}; dst[3] = v3;
}

// ---------------------------------------------------------------------------
// prepW: W1,W2 [3][64][256] f32 -> WcatT [256 o][384 k] bf16
// k-block order: x->W1[0], h->W2[0], T1x->W1[1], T1h->W2[1], T2x->W1[2], T2h->W2[2]
// ---------------------------------------------------------------------------
__global__ __launch_bounds__(256) void k_prepW(const float* __restrict__ W1,
                                               const float* __restrict__ W2,
                                               unsigned short* __restrict__ WcatT) {
  int tid = blockIdx.x * 256 + threadIdx.x;   // 49152 threads
  int o = tid & 255;
  int kk = (tid >> 8) * 2;
  unsigned int out = 0;
#pragma unroll
  for (int j = 0; j < 2; ++j) {
    int k = kk + j;
    int kb = k >> 6, f = k & 63;
    const float* src = (kb & 1) ? W2 : W1;
    float v = src[(((kb >> 1) * 64 + f) << 8) + o];
    out |= ((unsigned int)f2bf(v)) << (16 * j);
  }
  *(unsigned int*)(WcatT + (size_t)o * 384 + kk) = out;
}

// ---------------------------------------------------------------------------
// gemmL<PASS>: P = L_b @ Rt_b  (Rt = [B][128][N] bf16, k-major)
//   PASS 1: T1row[b][n][c] = P ; T1T[b][c][n] = P
//   PASS 2: T2row[b][n][c] = 2*P - T0  (T0 = x|h f32)
// tile: 64 rows x 128 cols, BK=64, 4 waves (2x2), 16x16x32 bf16 MFMA
// ---------------------------------------------------------------------------
template <int PASS>
__global__ __launch_bounds__(256) void k_gemmL(
    const float* __restrict__ L, const unsigned short* __restrict__ Rt,
    unsigned short* __restrict__ T1row, unsigned short* __restrict__ T1T,
    unsigned short* __restrict__ T2row,
    const float* __restrict__ x, const float* __restrict__ h) {
  __shared__ __align__(16) unsigned short Ab[2][64 * 72];    // 144B rows (pad)
  __shared__ __align__(16) unsigned short Bbuf[2][128 * 64]; // linear + XOR swizzle
  const int b = blockIdx.y;
  const int n0 = blockIdx.x * 64;
  const int t = threadIdx.x;
  const int w = t >> 6, l = t & 63;
  const int wr = w >> 1, wc = w & 1;
  const int l15 = l & 15, l4 = l >> 4;

  const float* Lb = L + ((size_t)b * NN + n0) * NN;
  const unsigned short* Rb = Rt + (size_t)b * C2 * NN;

  f32x4 areg[2][4];
  u32x4 breg[4];
  f32x4 acc[2][4];
  f32x4 z = {0.f, 0.f, 0.f, 0.f};
#pragma unroll
  for (int i = 0; i < 2; ++i)
#pragma unroll
    for (int j = 0; j < 4; ++j) acc[i][j] = z;

#define LOAD_A(kt, ar)                                                     \
  {                                                                        \
    int k0 = (kt) * 64;                                                    \
    _Pragma("unroll") for (int i = 0; i < 4; ++i) {                        \
      int e = t + i * 256; int row = e >> 4, c4 = e & 15;                  \
      (ar)[i] = *(const f32x4*)(Lb + (size_t)row * NN + k0 + c4 * 4);      \
    }                                                                      \
  }
#define LOAD_B(kt, br)                                                     \
  {                                                                        \
    int k0 = (kt) * 64;                                                    \
    _Pragma("unroll") for (int i = 0; i < 4; ++i) {                        \
      int e = t + i * 256; int c = e >> 3, q = e & 7;                      \
      (br)[i] = *(const u32x4*)(Rb + (size_t)c * NN + k0 + q * 8);         \
    }                                                                      \
  }
#define STORE_A(p, ar)                                                     \
  {                                                                        \
    _Pragma("unroll") for (int i = 0; i < 4; ++i) {                        \
      int e = t + i * 256; int row = e >> 4, c4 = e & 15;                  \
      *(uint2*)&Ab[p][row * 72 + c4 * 4] =                                 \
          make_uint2(pack2((ar)[i].x, (ar)[i].y), pack2((ar)[i].z, (ar)[i].w)); \
    }                                                                      \
  }
#define STORE_B(p, br)                                                     \
  {                                                                        \
    _Pragma("unroll") for (int i = 0; i < 4; ++i) {                        \
      int e = t + i * 256; int c = e >> 3, q = e & 7;                      \
      int ks = (q * 8) ^ ((c & 7) << 3);                                   \
      *(u32x4*)&Bbuf[p][c * 64 + ks] = (br)[i];                            \
    }                                                                      \
  }

  LOAD_A(0, areg[0]);
  LOAD_B(0, breg);
  STORE_A(0, areg[0]);
  STORE_B(0, breg);
  LOAD_A(1, areg[1]);
  __syncthreads();

  const int NT = NN / 64;
  for (int kt = 0; kt < NT; ++kt) {
    const int p = kt & 1;
    if (kt + 2 < NT) LOAD_A(kt + 2, areg[p]);       // HBM, 2-deep prefetch
    if (kt + 1 < NT) LOAD_B(kt + 1, breg);          // L2-resident

    bf16x8 af[2][2], bfr[4][2];
#pragma unroll
    for (int rf = 0; rf < 2; ++rf)
#pragma unroll
      for (int ks = 0; ks < 2; ++ks) {
        int n = wr * 32 + rf * 16 + l15;
        af[rf][ks] = *(const bf16x8*)&Ab[p][n * 72 + ks * 32 + l4 * 8];
      }
#pragma unroll
    for (int cf = 0; cf < 4; ++cf)
#pragma unroll
      for (int ks = 0; ks < 2; ++ks) {
        int c = wc * 64 + cf * 16 + l15;
        int kk = (ks * 32 + l4 * 8) ^ ((c & 7) << 3);
        bfr[cf][ks] = *(const bf16x8*)&Bbuf[p][c * 64 + kk];
      }
#pragma unroll
    for (int ks = 0; ks < 2; ++ks)
#pragma unroll
      for (int rf = 0; rf < 2; ++rf)
#pragma unroll
        for (int cf = 0; cf < 4; ++cf)
          acc[rf][cf] = __builtin_amdgcn_mfma_f32_16x16x32_bf16(
              af[rf][ks], bfr[cf][ks], acc[rf][cf], 0, 0, 0);

    if (kt + 1 < NT) {
      STORE_A(p ^ 1, areg[(kt + 1) & 1]);
      STORE_B(p ^ 1, breg);
    }
    __syncthreads();
  }

  // epilogue
#pragma unroll
  for (int rf = 0; rf < 2; ++rf)
#pragma unroll
    for (int cf = 0; cf < 4; ++cf) {
      int c = wc * 64 + cf * 16 + l15;
      int nb = n0 + wr * 32 + rf * 16 + l4 * 4;
      f32x4 v = acc[rf][cf];
      if (PASS == 1) {
#pragma unroll
        for (int r = 0; r < 4; ++r)
          T1row[((size_t)b * NN + nb + r) * C2 + c] = f2bf(v[r]);
        *(uint2*)(T1T + ((size_t)b * C2 + c) * NN + nb) =
            make_uint2(pack2(v[0], v[1]), pack2(v[2], v[3]));
      } else {
#pragma unroll
        for (int r = 0; r < 4; ++r) {
          int n = nb + r;
          float t0 = (c < 64) ? x[(((size_t)b * NN + n) << 6) + c]
                              : h[(((size_t)b * NN + n) << 6) + (c - 64)];
          T2row[((size_t)b * NN + n) * C2 + c] = f2bf(2.0f * v[r] - t0);
        }
      }
    }
#undef LOAD_A
#undef LOAD_B
#undef STORE_A
#undef STORE_B
}

// ---------------------------------------------------------------------------
// final: combined = [feat 384] @ WcatT^T + b1 + b2 ; LSTM gates ; write h,c
// block: 64 rows x 256 cols, 4 waves (16 rows each), BK=32, 12 K-steps
// ---------------------------------------------------------------------------
__global__ __launch_bounds__(256) void k_final(
    const float* __restrict__ x, const float* __restrict__ h,
    const unsigned short* __restrict__ T1row, const unsigned short* __restrict__ T2row,
    const unsigned short* __restrict__ WcatT,
    const float* __restrict__ b1, const float* __restrict__ b2,
    const float* __restrict__ c_cur, float* __restrict__ out) {
  __shared__ __align__(16) unsigned short Al[64 * 40];   // 80B rows
  __shared__ __align__(16) unsigned short Bl[256 * 40];
  const int t = threadIdx.x;
  const int w = t >> 6, l = t & 63;
  const int l15 = l & 15, l4 = l >> 4;
  const int gr0 = blockIdx.x * 64;
  const int b = gr0 >> 12, n0 = gr0 & (NN - 1);

  f32x4 acc[16];
  f32x4 z = {0.f, 0.f, 0.f, 0.f};
#pragma unroll
  for (int i = 0; i < 16; ++i) acc[i] = z;

  for (int kt = 0; kt < 12; ++kt) {
    const int sb = kt >> 1;
    const int cb = (kt & 1) * 32;
    __syncthreads();
    if (sb < 2) {
      const float* src = (sb == 0) ? x : h;
#pragma unroll
      for (int i = 0; i < 2; ++i) {
        int e = t + i * 256; int n = e >> 3, q = e & 7;
        f32x4 v = *(const f32x4*)(src + (((size_t)b * NN + n0 + n) << 6) + cb + q * 4);
        *(uint2*)&Al[n * 40 + q * 4] = make_uint2(pack2(v.x, v.y), pack2(v.z, v.w));
      }
    } else {
      const unsigned short* src = (sb < 4) ? T1row : T2row;
      int c0 = ((sb & 1) ? 64 : 0) + cb;
      int n = t >> 2, q = t & 3;
      u32x4 v = *(const u32x4*)(src + ((size_t)b * NN + n0 + n) * C2 + c0 + q * 8);
      *(u32x4*)&Al[n * 40 + q * 8] = v;
    }
    {
      int o0 = t >> 2, q = t & 3;
#pragma unroll
      for (int i = 0; i < 4; ++i) {
        int o = o0 + i * 64;
        u32x4 v = *(const u32x4*)(WcatT + (size_t)o * 384 + kt * 32 + q * 8);
        *(u32x4*)&Bl[o * 40 + q * 8] = v;
      }
    }
    __syncthreads();
    bf16x8 afr = *(const bf16x8*)&Al[(w * 16 + l15) * 40 + l4 * 8];
#pragma unroll
    for (int cf = 0; cf < 16; ++cf) {
      bf16x8 bfr = *(const bf16x8*)&Bl[(cf * 16 + l15) * 40 + l4 * 8];
      acc[cf] = __builtin_amdgcn_mfma_f32_16x16x32_bf16(afr, bfr, acc[cf], 0, 0, 0);
    }
  }

  const int nrow = n0 + w * 16 + l4 * 4;
#pragma unroll
  for (int cf = 0; cf < 4; ++cf) {
    int j = cf * 16 + l15;
    float bi = b1[j] + b2[j];
    float bf_ = b1[64 + j] + b2[64 + j];
    float bo = b1[128 + j] + b2[128 + j];
    float bg = b1[192 + j] + b2[192 + j];
#pragma unroll
    for (int r = 0; r < 4; ++r) {
      int n = nrow + r;
      size_t base = ((size_t)b * NN + n) * HH + j;
      float ii = acc[cf][r] + bi;
      float ff = acc[cf + 4][r] + bf_;
      float oo = acc[cf + 8][r] + bo;
      float gg = acc[cf + 12][r] + bg;
      ii = 1.0f / (1.0f + __expf(-ii));
      ff = 1.0f / (1.0f + __expf(-ff));
      oo = 1.0f / (1.0f + __expf(-oo));
      gg = tanhf(gg);
      float cn = ff * c_cur[base] + ii * gg;
      float hn = oo * tanhf(cn);
      out[base] = hn;
      out[(size_t)BB * NN * HH + base] = cn;
    }
  }
}

// ---------------------------------------------------------------------------
extern "C" void kernel_launch(void* const* d_in, const int* in_sizes, int n_in,
                              void* d_out, int out_size, void* d_ws, size_t ws_size,
                              hipStream_t stream) {
  const float* x  = (const float*)d_in[0];
  const float* L  = (const float*)d_in[1];
  const float* h  = (const float*)d_in[2];
  const float* c  = (const float*)d_in[3];
  const float* W1 = (const float*)d_in[4];
  const float* b1 = (const float*)d_in[5];
  const float* W2 = (const float*)d_in[6];
  const float* b2 = (const float*)d_in[7];
  char* ws = (char*)d_ws;
  unsigned short* XbfT  = (unsigned short*)(ws);                       // 8 MB
  unsigned short* T1row = (unsigned short*)(ws + (size_t)(8u << 20));  // 8 MB
  unsigned short* T1T   = (unsigned short*)(ws + (size_t)(16u << 20)); // 8 MB
  unsigned short* T2row = (unsigned short*)(ws + (size_t)(24u << 20)); // 8 MB
  unsigned short* WcatT = (unsigned short*)(ws + (size_t)(32u << 20)); // 192 KB
  float* out = (float*)d_out;

  k_prepX<<<dim3(64, 8), 256, 0, stream>>>(x, h, XbfT);
  k_prepW<<<dim3(192), 256, 0, stream>>>(W1, W2, WcatT);
  k_gemmL<1><<<dim3(64, 8), 256, 0, stream>>>(L, XbfT, T1row, T1T, nullptr, x, h);
  k_gemmL<2><<<dim3(64, 8), 256, 0, stream>>>(L, T1T, nullptr, nullptr, T2row, x, h);
  k_final<<<dim3(512), 256, 0, stream>>>(x, h, T1row, T2row, WcatT, b1, b2, c, out);
}